// Round 3
// baseline (2762.829 us; speedup 1.0000x reference)
//
#include <hip/hip_runtime.h>
#include <cstdint>
#include <cstddef>

// ---------------------------------------------------------------------------
// DualAttention: B=1024, L=196, H=1024, A=512
// R3: both GEMM kernels use reg-prefetch pipelining (issue next tile's global
// loads AFTER the barrier so they overlap MFMA and drain at the next barrier).
// k_channel stages its transposed A-tile (64h x 224l bf16) ONCE per block.
// ---------------------------------------------------------------------------

#define DEVI __device__ __forceinline__

typedef __bf16 bf16;
typedef bf16 bf16x4 __attribute__((ext_vector_type(4)));
typedef bf16 bf16x8 __attribute__((ext_vector_type(8)));
typedef float f32x4 __attribute__((ext_vector_type(4)));
typedef unsigned int uint32;

static constexpr int Bb = 1024;
static constexpr int Ll = 196;
static constexpr int Hh = 1024;
static constexpr int BL = Bb * Ll;        // 200704
static constexpr int LPAD = 224;          // 7*32

DEVI float fast_tanh(float x) {
  float e = __expf(2.f * x);
  return 1.f - 2.f * __builtin_amdgcn_rcpf(e + 1.f);
}

DEVI uint32 packbf2(float a, float b) {
  union { bf16 h; unsigned short u; } x, y;
  x.h = (bf16)a; y.h = (bf16)b;
  return (uint32)x.u | ((uint32)y.u << 16);
}

// --------------------- weight panel builders (run once) --------------------
// Panels: [k0/32][a=0..511][64B]; 16B slot s holds k-octet (s ^ g(a)),
// g(a) = (a>>1)&3  (XOR baked at build; GEMM reads slot l4^g).
__global__ void k_build_wt(const float* __restrict__ W, bf16* __restrict__ P) {
  int idx = blockIdx.x * 256 + threadIdx.x;      // 65536
  int a = idx & 511;
  int ko = (idx >> 9) << 3;
  bf16x8 v;
#pragma unroll
  for (int j = 0; j < 8; ++j) v[j] = (bf16)W[(size_t)(ko + j) * 512 + a];
  int panel = ko >> 5;
  int slot = ((ko >> 3) & 3) ^ ((a >> 1) & 3);
  *reinterpret_cast<bf16x8*>((char*)P + (size_t)panel * 32768 + a * 64 + slot * 16) = v;
}

__global__ void k_build_wct(const float* __restrict__ W, bf16* __restrict__ P) {
  int idx = blockIdx.x * 256 + threadIdx.x;      // 14336
  int a = idx & 511;
  int lo = (idx >> 9) << 3;
  bf16x8 v;
#pragma unroll
  for (int j = 0; j < 8; ++j)
    v[j] = (lo + j < Ll) ? (bf16)W[(size_t)(lo + j) * 512 + a] : (bf16)0.f;
  int panel = lo >> 5;
  int slot = ((lo >> 3) & 3) ^ ((a >> 1) & 3);
  *reinterpret_cast<bf16x8*>((char*)P + (size_t)panel * 32768 + a * 64 + slot * 16) = v;
}

// ------------------------------- p_h = h@W_h -------------------------------
__global__ void k_ph(const float* __restrict__ h, const float* __restrict__ W_h,
                     const float* __restrict__ b_h, float* __restrict__ p_h) {
  int a = blockIdx.x * 256 + threadIdx.x;
  int b0 = blockIdx.y * 8;
  float acc[8] = {0.f, 0.f, 0.f, 0.f, 0.f, 0.f, 0.f, 0.f};
  for (int k = 0; k < 1024; ++k) {
    float w = W_h[(size_t)k * 512 + a];
#pragma unroll
    for (int i = 0; i < 8; ++i) acc[i] += h[(size_t)(b0 + i) * 1024 + k] * w;
  }
#pragma unroll
  for (int i = 0; i < 8; ++i) p_h[(size_t)(b0 + i) * 512 + a] = acc[i] + b_h[a];
}

// ---------------- spatial branch: fused GEMM + tanh-dot reduce -------------
// grid = BL/64 = 3136, 256 thr; tile 64 x 512, K=1024, 32 steps.
// Reg-prefetch A (2 float4) and B (8 dwordx4) for step t+1 after the barrier.
#define SP_AOFF 32768
#define SP_ASTR 80
__launch_bounds__(256, 2)
__global__ void k_spatial(const float* __restrict__ att, const bf16* __restrict__ WtP,
                          const float* __restrict__ b_att, const float* __restrict__ p_h,
                          const float* __restrict__ w_alpha, float* __restrict__ logits_s) {
  __shared__ alignas(1024) char lds[SP_AOFF + 64 * SP_ASTR];
  const int tid = threadIdx.x;
  const int lane = tid & 63;
  const int wn = tid >> 6;
  const int l15 = lane & 15, l4 = lane >> 4;
  const size_t row0 = (size_t)blockIdx.x * 64;
  const int slotB = ((l4 ^ ((l15 >> 1) & 3)) << 4);
  const int ar = tid >> 2;                  // A rows 0..63
  const int aks = (tid & 3) << 3;           // k offset 0,8,16,24
  const char* WtPc = (const char*)WtP;

  f32x4 acc[4][8];
#pragma unroll
  for (int m = 0; m < 4; ++m)
#pragma unroll
    for (int n = 0; n < 8; ++n) acc[m][n] = f32x4{0.f, 0.f, 0.f, 0.f};

  uint4 bpf[8];
  float4 apf0, apf1;
  // prologue: prefetch k-step 0
  {
    const char* bsrc = WtPc;
#pragma unroll
    for (int j = 0; j < 8; ++j)
      bpf[j] = *reinterpret_cast<const uint4*>(bsrc + j * 4096 + tid * 16);
    const float* ap = att + (row0 + ar) * 1024 + aks;
    apf0 = *reinterpret_cast<const float4*>(ap);
    apf1 = *reinterpret_cast<const float4*>(ap + 4);
  }

  for (int t = 0; t < 32; ++t) {
    // write stage (auto vmcnt-waits on the prefetched regs)
    bf16x4 w0 = {(bf16)apf0.x, (bf16)apf0.y, (bf16)apf0.z, (bf16)apf0.w};
    bf16x4 w1 = {(bf16)apf1.x, (bf16)apf1.y, (bf16)apf1.z, (bf16)apf1.w};
    *reinterpret_cast<bf16x4*>(&lds[SP_AOFF + ar * SP_ASTR + (aks << 1)]) = w0;
    *reinterpret_cast<bf16x4*>(&lds[SP_AOFF + ar * SP_ASTR + (aks << 1) + 8]) = w1;
#pragma unroll
    for (int j = 0; j < 8; ++j)
      *reinterpret_cast<uint4*>(&lds[j * 4096 + tid * 16]) = bpf[j];
    __syncthreads();
    // prefetch next step: in flight during MFMA, drained at next barrier
    if (t < 31) {
      const char* bsrc = WtPc + (size_t)(t + 1) * 32768;
#pragma unroll
      for (int j = 0; j < 8; ++j)
        bpf[j] = *reinterpret_cast<const uint4*>(bsrc + j * 4096 + tid * 16);
      const float* ap = att + (row0 + ar) * 1024 + (t + 1) * 32 + aks;
      apf0 = *reinterpret_cast<const float4*>(ap);
      apf1 = *reinterpret_cast<const float4*>(ap + 4);
    }
    bf16x8 af[4];
#pragma unroll
    for (int m = 0; m < 4; ++m)
      af[m] = *reinterpret_cast<const bf16x8*>(
          &lds[SP_AOFF + (m * 16 + l15) * SP_ASTR + (l4 << 4)]);
#pragma unroll
    for (int n = 0; n < 8; ++n) {
      bf16x8 bv = *reinterpret_cast<const bf16x8*>(
          &lds[(wn * 128 + n * 16 + l15) * 64 + slotB]);
#pragma unroll
      for (int m = 0; m < 4; ++m)
        acc[m][n] = __builtin_amdgcn_mfma_f32_16x16x32_bf16(af[m], bv, acc[m][n], 0, 0, 0);
    }
    __syncthreads();
  }

  // epilogue
  float wa[8], ba[8], ph0[8], ph1[8];
  int cols[8];
  unsigned b0i = (unsigned)row0 / 196u;
  unsigned b1i = (unsigned)(row0 + 63) / 196u;
  unsigned bnd = (b0i + 1) * 196u;
#pragma unroll
  for (int n = 0; n < 8; ++n) {
    int a = wn * 128 + n * 16 + l15;
    cols[n] = a;
    wa[n] = w_alpha[a];
    ba[n] = b_att[a];
    ph0[n] = p_h[(size_t)b0i * 512 + a];
    ph1[n] = p_h[(size_t)b1i * 512 + a];
  }
  float* red = reinterpret_cast<float*>(lds);
#pragma unroll
  for (int m = 0; m < 4; ++m) {
#pragma unroll
    for (int j = 0; j < 4; ++j) {
      int rloc = m * 16 + l4 * 4 + j;
      unsigned R = (unsigned)row0 + rloc;
      bool hib = R >= bnd;
      float s = 0.f;
#pragma unroll
      for (int n = 0; n < 8; ++n)
        s += fast_tanh(acc[m][n][j] + ba[n] + (hib ? ph1[n] : ph0[n])) * wa[n];
      s += __shfl_xor(s, 1);
      s += __shfl_xor(s, 2);
      s += __shfl_xor(s, 4);
      s += __shfl_xor(s, 8);
      if (l15 == 0) red[wn * 64 + rloc] = s;
    }
  }
  __syncthreads();
  if (tid < 64)
    logits_s[row0 + tid] = red[tid] + red[64 + tid] + red[128 + tid] + red[192 + tid];
}

// ---------------- channel branch: fused GEMM + tanh-dot reduce -------------
// grid = (16 h-tiles, 1024 b), 256 thr. A-tile (64h x 224l bf16) staged ONCE
// per block via pair-packed transpose; K-loop (7 steps) reg-prefetches B only.
#define CH_AOFF 32768
#define CH_ASTR 464              /* 29*16: b128-aligned rows, spread quads */
__launch_bounds__(256, 2)
__global__ void k_channel(const float* __restrict__ att, const bf16* __restrict__ WctP,
                          const float* __restrict__ b_ch, const float* __restrict__ p_h,
                          const float* __restrict__ w_beta, float* __restrict__ logits_c) {
  __shared__ alignas(1024) char lds[CH_AOFF + 64 * CH_ASTR];
  const int tid = threadIdx.x;
  const int lane = tid & 63;
  const int wn = tid >> 6;
  const int l15 = lane & 15, l4 = lane >> 4;
  const int b = blockIdx.y;
  const int h0 = blockIdx.x * 64;
  const float* attb = att + (size_t)b * Ll * 1024;
  const int slotB = ((l4 ^ ((l15 >> 1) & 3)) << 4);
  const char* WctPc = (const char*)WctP;

  f32x4 acc[4][8];
#pragma unroll
  for (int m = 0; m < 4; ++m)
#pragma unroll
    for (int n = 0; n < 8; ++n) acc[m][n] = f32x4{0.f, 0.f, 0.f, 0.f};

  // ---- A-stage, once: transpose att[b][l][h0..h0+63] -> lds[h][l] bf16 ----
  {
    const int lsub = tid >> 4;               // l-pair 0..15
    const int hq = (tid & 15) << 2;          // h 0,4,...,60
#pragma unroll
    for (int ch = 0; ch < 7; ++ch) {
      int lg = ch * 32 + 2 * lsub;
      float4 va = {0.f, 0.f, 0.f, 0.f}, vb = {0.f, 0.f, 0.f, 0.f};
      if (lg < Ll)
        va = *reinterpret_cast<const float4*>(&attb[(size_t)lg * 1024 + h0 + hq]);
      if (lg + 1 < Ll)
        vb = *reinterpret_cast<const float4*>(&attb[(size_t)(lg + 1) * 1024 + h0 + hq]);
      uint32 p0 = packbf2(va.x, vb.x), p1 = packbf2(va.y, vb.y);
      uint32 p2 = packbf2(va.z, vb.z), p3 = packbf2(va.w, vb.w);
      char* abase = &lds[CH_AOFF + hq * CH_ASTR + lg * 2];
      *reinterpret_cast<uint32*>(abase) = p0;
      *reinterpret_cast<uint32*>(abase + CH_ASTR) = p1;
      *reinterpret_cast<uint32*>(abase + 2 * CH_ASTR) = p2;
      *reinterpret_cast<uint32*>(abase + 3 * CH_ASTR) = p3;
    }
  }
  // ---- B prologue prefetch (panel 0) ----
  uint4 bpf[8];
#pragma unroll
  for (int j = 0; j < 8; ++j)
    bpf[j] = *reinterpret_cast<const uint4*>(WctPc + j * 4096 + tid * 16);
  __syncthreads();                            // A-tile ready

  for (int t7 = 0; t7 < 7; ++t7) {
#pragma unroll
    for (int j = 0; j < 8; ++j)
      *reinterpret_cast<uint4*>(&lds[j * 4096 + tid * 16]) = bpf[j];
    __syncthreads();
    if (t7 < 6) {
      const char* bsrc = WctPc + (size_t)(t7 + 1) * 32768;
#pragma unroll
      for (int j = 0; j < 8; ++j)
        bpf[j] = *reinterpret_cast<const uint4*>(bsrc + j * 4096 + tid * 16);
    }
    bf16x8 af[4];
#pragma unroll
    for (int m = 0; m < 4; ++m)
      af[m] = *reinterpret_cast<const bf16x8*>(
          &lds[CH_AOFF + (m * 16 + l15) * CH_ASTR + t7 * 64 + (l4 << 4)]);
#pragma unroll
    for (int n = 0; n < 8; ++n) {
      bf16x8 bv = *reinterpret_cast<const bf16x8*>(
          &lds[(wn * 128 + n * 16 + l15) * 64 + slotB]);
#pragma unroll
      for (int m = 0; m < 4; ++m)
        acc[m][n] = __builtin_amdgcn_mfma_f32_16x16x32_bf16(af[m], bv, acc[m][n], 0, 0, 0);
    }
    __syncthreads();
  }

  // epilogue
  float wb[8], bc[8], ph[8];
#pragma unroll
  for (int n = 0; n < 8; ++n) {
    int a = wn * 128 + n * 16 + l15;
    wb[n] = w_beta[a];
    bc[n] = b_ch[a];
    ph[n] = p_h[(size_t)b * 512 + a];
  }
  float* red = reinterpret_cast<float*>(lds);
#pragma unroll
  for (int m = 0; m < 4; ++m) {
#pragma unroll
    for (int j = 0; j < 4; ++j) {
      int rloc = m * 16 + l4 * 4 + j;
      float s = 0.f;
#pragma unroll
      for (int n = 0; n < 8; ++n)
        s += fast_tanh(acc[m][n][j] + bc[n] + ph[n]) * wb[n];
      s += __shfl_xor(s, 1);
      s += __shfl_xor(s, 2);
      s += __shfl_xor(s, 4);
      s += __shfl_xor(s, 8);
      if (l15 == 0) red[wn * 64 + rloc] = s;
    }
  }
  __syncthreads();
  if (tid < 64)
    logits_c[(size_t)b * 1024 + h0 + tid] =
        red[tid] + red[64 + tid] + red[128 + tid] + red[192 + tid];
}

// ------------------------------- softmaxes ---------------------------------
__global__ void k_softmax_s(const float* __restrict__ logits, float* __restrict__ wout) {
  int b = blockIdx.x, t = threadIdx.x;
  __shared__ float sm[8];
  float x = (t < Ll) ? logits[(size_t)b * Ll + t] : -1e30f;
  float m = x;
#pragma unroll
  for (int o = 32; o; o >>= 1) m = fmaxf(m, __shfl_xor(m, o));
  if ((t & 63) == 0) sm[t >> 6] = m;
  __syncthreads();
  m = fmaxf(fmaxf(sm[0], sm[1]), fmaxf(sm[2], sm[3]));
  float e = (t < Ll) ? __expf(x - m) : 0.f;
  float s = e;
#pragma unroll
  for (int o = 32; o; o >>= 1) s += __shfl_xor(s, o);
  if ((t & 63) == 0) sm[4 + (t >> 6)] = s;
  __syncthreads();
  s = sm[4] + sm[5] + sm[6] + sm[7];
  if (t < Ll) wout[(size_t)b * Ll + t] = e / s;
}

__global__ void k_softmax_c(const float* __restrict__ logits, float* __restrict__ wout) {
  int b = blockIdx.x, t = threadIdx.x;
  __shared__ float sm[8];
  float4 x = *reinterpret_cast<const float4*>(&logits[(size_t)b * 1024 + (t << 2)]);
  float m = fmaxf(fmaxf(x.x, x.y), fmaxf(x.z, x.w));
#pragma unroll
  for (int o = 32; o; o >>= 1) m = fmaxf(m, __shfl_xor(m, o));
  if ((t & 63) == 0) sm[t >> 6] = m;
  __syncthreads();
  m = fmaxf(fmaxf(sm[0], sm[1]), fmaxf(sm[2], sm[3]));
  float e0 = __expf(x.x - m), e1 = __expf(x.y - m);
  float e2 = __expf(x.z - m), e3 = __expf(x.w - m);
  float s = e0 + e1 + e2 + e3;
#pragma unroll
  for (int o = 32; o; o >>= 1) s += __shfl_xor(s, o);
  if ((t & 63) == 0) sm[4 + (t >> 6)] = s;
  __syncthreads();
  float r = 1.f / (sm[4] + sm[5] + sm[6] + sm[7]);
  float4 o4 = {e0 * r, e1 * r, e2 * r, e3 * r};
  *reinterpret_cast<float4*>(&wout[(size_t)b * 1024 + (t << 2)]) = o4;
}

// --------------- fused weighted sums: one pass over att --------------------
__launch_bounds__(256)
__global__ void k_weighted(const float* __restrict__ att, const float* __restrict__ wsp,
                           const float* __restrict__ wch, float* __restrict__ out_s,
                           float* __restrict__ out_c) {
  int b = blockIdx.x, t = threadIdx.x;
  int lane = t & 63, wave = t >> 6;
  __shared__ float wsl[Ll];
  __shared__ float chan[4][Ll];
  if (t < Ll) wsl[t] = wsp[(size_t)b * Ll + t];
  float4 wc = *reinterpret_cast<const float4*>(&wch[(size_t)b * 1024 + (t << 2)]);
  float4 accs = {0.f, 0.f, 0.f, 0.f};
  __syncthreads();
  const float* attb = att + (size_t)b * Ll * 1024;
  for (int l = 0; l < Ll; ++l) {
    float4 v = *reinterpret_cast<const float4*>(&attb[(size_t)l * 1024 + (t << 2)]);
    float w = wsl[l];
    accs.x += w * v.x; accs.y += w * v.y; accs.z += w * v.z; accs.w += w * v.w;
    float pc = wc.x * v.x + wc.y * v.y + wc.z * v.z + wc.w * v.w;
#pragma unroll
    for (int o = 32; o; o >>= 1) pc += __shfl_xor(pc, o);
    if (lane == 0) chan[wave][l] = pc;
  }
  *reinterpret_cast<float4*>(&out_s[(size_t)b * 1024 + (t << 2)]) = accs;
  __syncthreads();
  if (t < Ll)
    out_c[(size_t)b * Ll + t] = chan[0][t] + chan[1][t] + chan[2][t] + chan[3][t];
}

// ------------------------------- launcher ----------------------------------
extern "C" void kernel_launch(void* const* d_in, const int* in_sizes, int n_in,
                              void* d_out, int out_size, void* d_ws, size_t ws_size,
                              hipStream_t stream) {
  (void)in_sizes; (void)n_in; (void)out_size; (void)ws_size;
  const float* att     = (const float*)d_in[0];
  const float* h       = (const float*)d_in[1];
  const float* W_att   = (const float*)d_in[2];
  const float* b_att   = (const float*)d_in[3];
  const float* W_h     = (const float*)d_in[4];
  const float* b_h     = (const float*)d_in[5];
  const float* w_alpha = (const float*)d_in[6];
  const float* W_ch    = (const float*)d_in[8];
  const float* b_ch    = (const float*)d_in[9];
  const float* w_beta  = (const float*)d_in[10];
  // d_in[7] b_alpha, d_in[11] b_beta: softmax-shift-invariant, unused

  float* out_ws    = (float*)d_out;                       // [B,H]
  float* out_wc    = out_ws + (size_t)Bb * Hh;            // [B,L]
  float* out_wspat = out_wc + (size_t)Bb * Ll;            // [B,L]

  char* ws = (char*)d_ws;
  float* p_h      = (float*)(ws);                          // 2 MB
  float* logits_s = (float*)(ws + 2097152);                // 802816 B
  float* logits_c = (float*)(ws + 2899968);                // 4 MB
  float* w_chan   = (float*)(ws + 7094272);                // 4 MB
  bf16*  WtP      = (bf16*)(ws + 11288576);                // 1 MB (32 panels)
  bf16*  WctP     = (bf16*)(ws + 12337152);                // 224 KB (7 panels)

  k_build_wt<<<256, 256, 0, stream>>>(W_att, WtP);
  k_build_wct<<<56, 256, 0, stream>>>(W_ch, WctP);
  k_ph<<<dim3(2, 128), 256, 0, stream>>>(h, W_h, b_h, p_h);
  k_spatial<<<BL / 64, 256, 0, stream>>>(att, WtP, b_att, p_h, w_alpha, logits_s);
  k_channel<<<dim3(16, 1024), 256, 0, stream>>>(att, WctP, b_ch, p_h, w_beta, logits_c);
  k_softmax_s<<<1024, 256, 0, stream>>>(logits_s, out_wspat);
  k_softmax_c<<<1024, 256, 0, stream>>>(logits_c, w_chan);
  k_weighted<<<1024, 256, 0, stream>>>(att, out_wspat, w_chan, out_ws, out_wc);
}

// Round 4
// 1426.779 us; speedup vs baseline: 1.9364x; 1.9364x over previous
//
#include <hip/hip_runtime.h>
#include <cstdint>
#include <cstddef>

// ---------------------------------------------------------------------------
// DualAttention: B=1024, L=196, H=1024, A=512
// R4: pipeline state lives in LDS double-buffers (not registers!).
//  - k_spatial: B dbuf via global_load_lds (0 VGPR), A dbuf + depth-2 reg
//    pipe (8 VGPR), ONE barrier per k-step; loads issued before MFMA.
//  - k_channel: A-tile staged once (hoisted), B single-buf via
//    global_load_lds. No __launch_bounds__ min-wave caps anywhere (R3's
//    (256,2) caused 2.2 GB of scratch spill traffic).
// ---------------------------------------------------------------------------

#define DEVI __device__ __forceinline__

typedef __bf16 bf16;
typedef bf16 bf16x4 __attribute__((ext_vector_type(4)));
typedef bf16 bf16x8 __attribute__((ext_vector_type(8)));
typedef float f32x4 __attribute__((ext_vector_type(4)));
typedef unsigned int uint32;

static constexpr int Bb = 1024;
static constexpr int Ll = 196;
static constexpr int Hh = 1024;
static constexpr int BL = Bb * Ll;        // 200704

DEVI void async16(const void* g, void* l) {
  __builtin_amdgcn_global_load_lds(
      (const __attribute__((address_space(1))) void*)g,
      (__attribute__((address_space(3))) void*)l, 16, 0, 0);
}

DEVI float fast_tanh(float x) {
  float e = __expf(2.f * x);
  return 1.f - 2.f * __builtin_amdgcn_rcpf(e + 1.f);
}

DEVI uint32 packbf2(float a, float b) {
  union { bf16 h; unsigned short u; } x, y;
  x.h = (bf16)a; y.h = (bf16)b;
  return (uint32)x.u | ((uint32)y.u << 16);
}

// --------------------- weight panel builders (run once) --------------------
// Panels: [k0/32][a=0..511][64B]; 16B slot s holds k-octet (s ^ g(a)),
// g(a) = (a>>1)&3  (XOR baked at build; GEMM reads slot l4^g).
__global__ void k_build_wt(const float* __restrict__ W, bf16* __restrict__ P) {
  int idx = blockIdx.x * 256 + threadIdx.x;      // 65536
  int a = idx & 511;
  int ko = (idx >> 9) << 3;
  bf16x8 v;
#pragma unroll
  for (int j = 0; j < 8; ++j) v[j] = (bf16)W[(size_t)(ko + j) * 512 + a];
  int panel = ko >> 5;
  int slot = ((ko >> 3) & 3) ^ ((a >> 1) & 3);
  *reinterpret_cast<bf16x8*>((char*)P + (size_t)panel * 32768 + a * 64 + slot * 16) = v;
}

__global__ void k_build_wct(const float* __restrict__ W, bf16* __restrict__ P) {
  int idx = blockIdx.x * 256 + threadIdx.x;      // 14336
  int a = idx & 511;
  int lo = (idx >> 9) << 3;
  bf16x8 v;
#pragma unroll
  for (int j = 0; j < 8; ++j)
    v[j] = (lo + j < Ll) ? (bf16)W[(size_t)(lo + j) * 512 + a] : (bf16)0.f;
  int panel = lo >> 5;
  int slot = ((lo >> 3) & 3) ^ ((a >> 1) & 3);
  *reinterpret_cast<bf16x8*>((char*)P + (size_t)panel * 32768 + a * 64 + slot * 16) = v;
}

// ------------------------------- p_h = h@W_h -------------------------------
__global__ void k_ph(const float* __restrict__ h, const float* __restrict__ W_h,
                     const float* __restrict__ b_h, float* __restrict__ p_h) {
  int a = blockIdx.x * 256 + threadIdx.x;
  int b0 = blockIdx.y * 8;
  float acc[8] = {0.f, 0.f, 0.f, 0.f, 0.f, 0.f, 0.f, 0.f};
  for (int k = 0; k < 1024; ++k) {
    float w = W_h[(size_t)k * 512 + a];
#pragma unroll
    for (int i = 0; i < 8; ++i) acc[i] += h[(size_t)(b0 + i) * 1024 + k] * w;
  }
#pragma unroll
  for (int i = 0; i < 8; ++i) p_h[(size_t)(b0 + i) * 512 + a] = acc[i] + b_h[a];
}

// ---------------- spatial branch: fused GEMM + tanh-dot reduce -------------
// grid = BL/64 = 3136, 256 thr; tile 64 x 512, K=1024, 32 steps.
// LDS: B dbuf 2x32KB at 0, A dbuf 2x5120B at 65536.  One barrier per step.
#define SPB(p) ((p) * 32768)
#define SPA(p) (65536 + (p) * 5120)
#define SP_ASTR 80
__launch_bounds__(256)
__global__ void k_spatial(const float* __restrict__ att, const bf16* __restrict__ WtP,
                          const float* __restrict__ b_att, const float* __restrict__ p_h,
                          const float* __restrict__ w_alpha, float* __restrict__ logits_s) {
  __shared__ alignas(1024) char lds[65536 + 2 * 5120];
  const int tid = threadIdx.x;
  const int lane = tid & 63;
  const int wn = tid >> 6;
  const int l15 = lane & 15, l4 = lane >> 4;
  const size_t row0 = (size_t)blockIdx.x * 64;
  const int slotB = ((l4 ^ ((l15 >> 1) & 3)) << 4);
  const int ar = tid >> 2;                  // A rows 0..63
  const int aks = (tid & 3) << 3;           // k offset 0,8,16,24
  const char* WtPc = (const char*)WtP;
  const float* apbase = att + (row0 + ar) * 1024 + aks;
  const int awoff = ar * SP_ASTR + (aks << 1);

  f32x4 acc[4][8];
#pragma unroll
  for (int m = 0; m < 4; ++m)
#pragma unroll
    for (int n = 0; n < 8; ++n) acc[m][n] = f32x4{0.f, 0.f, 0.f, 0.f};

  // prologue: A0 -> regs -> Abuf0; B0 glls -> Bbuf0; A1 -> regs
  float4 c0 = *reinterpret_cast<const float4*>(apbase);
  float4 c1 = *reinterpret_cast<const float4*>(apbase + 4);
#pragma unroll
  for (int j = 0; j < 8; ++j) {
    int c = (j << 2) + wn;
    async16(WtPc + c * 1024 + lane * 16, &lds[SPB(0) + c * 1024]);
  }
  {
    bf16x4 w0 = {(bf16)c0.x, (bf16)c0.y, (bf16)c0.z, (bf16)c0.w};
    bf16x4 w1 = {(bf16)c1.x, (bf16)c1.y, (bf16)c1.z, (bf16)c1.w};
    *reinterpret_cast<bf16x4*>(&lds[SPA(0) + awoff]) = w0;
    *reinterpret_cast<bf16x4*>(&lds[SPA(0) + awoff + 8]) = w1;
  }
  c0 = *reinterpret_cast<const float4*>(apbase + 32);
  c1 = *reinterpret_cast<const float4*>(apbase + 36);
  __syncthreads();

  for (int t = 0; t < 32; ++t) {
    const int p = t & 1;
    if (t < 31) {
      // write A(t+1) (regs arrived >=1 step ago)
      bf16x4 w0 = {(bf16)c0.x, (bf16)c0.y, (bf16)c0.z, (bf16)c0.w};
      bf16x4 w1 = {(bf16)c1.x, (bf16)c1.y, (bf16)c1.z, (bf16)c1.w};
      *reinterpret_cast<bf16x4*>(&lds[SPA(p ^ 1) + awoff]) = w0;
      *reinterpret_cast<bf16x4*>(&lds[SPA(p ^ 1) + awoff + 8]) = w1;
      // issue B(t+1) glls
      const char* bsrc = WtPc + (size_t)(t + 1) * 32768;
#pragma unroll
      for (int j = 0; j < 8; ++j) {
        int c = (j << 2) + wn;
        async16(bsrc + c * 1024 + lane * 16, &lds[SPB(p ^ 1) + c * 1024]);
      }
      // issue A(t+2) loads
      if (t < 30) {
        c0 = *reinterpret_cast<const float4*>(apbase + (t + 2) * 32);
        c1 = *reinterpret_cast<const float4*>(apbase + (t + 2) * 32 + 4);
      }
    }
    bf16x8 af[4];
#pragma unroll
    for (int m = 0; m < 4; ++m)
      af[m] = *reinterpret_cast<const bf16x8*>(
          &lds[SPA(p) + (m * 16 + l15) * SP_ASTR + (l4 << 4)]);
#pragma unroll
    for (int n = 0; n < 8; ++n) {
      bf16x8 bv = *reinterpret_cast<const bf16x8*>(
          &lds[SPB(p) + (wn * 128 + n * 16 + l15) * 64 + slotB]);
#pragma unroll
      for (int m = 0; m < 4; ++m)
        acc[m][n] = __builtin_amdgcn_mfma_f32_16x16x32_bf16(af[m], bv, acc[m][n], 0, 0, 0);
    }
    __syncthreads();
  }

  // epilogue
  float wa[8], ba[8], ph0[8], ph1[8];
  unsigned b0i = (unsigned)row0 / 196u;
  unsigned b1i = (unsigned)(row0 + 63) / 196u;
  unsigned bnd = (b0i + 1) * 196u;
#pragma unroll
  for (int n = 0; n < 8; ++n) {
    int a = wn * 128 + n * 16 + l15;
    wa[n] = w_alpha[a];
    ba[n] = b_att[a];
    ph0[n] = p_h[(size_t)b0i * 512 + a];
    ph1[n] = p_h[(size_t)b1i * 512 + a];
  }
  float* red = reinterpret_cast<float*>(lds);    // Bbuf0, safe after last barrier
#pragma unroll
  for (int m = 0; m < 4; ++m) {
#pragma unroll
    for (int j = 0; j < 4; ++j) {
      int rloc = m * 16 + l4 * 4 + j;
      unsigned R = (unsigned)row0 + rloc;
      bool hib = R >= bnd;
      float s = 0.f;
#pragma unroll
      for (int n = 0; n < 8; ++n)
        s += fast_tanh(acc[m][n][j] + ba[n] + (hib ? ph1[n] : ph0[n])) * wa[n];
      s += __shfl_xor(s, 1);
      s += __shfl_xor(s, 2);
      s += __shfl_xor(s, 4);
      s += __shfl_xor(s, 8);
      if (l15 == 0) red[wn * 64 + rloc] = s;
    }
  }
  __syncthreads();
  if (tid < 64)
    logits_s[row0 + tid] = red[tid] + red[64 + tid] + red[128 + tid] + red[192 + tid];
}

// ---------------- channel branch: fused GEMM + tanh-dot reduce -------------
// grid = (16 h-tiles, 1024 b), 256 thr. A-tile (64h x 224l bf16, 464B stride)
// staged ONCE; B panels single-buffered via global_load_lds, 7 steps.
#define CH_AOFF 32768
#define CH_ASTR 464
__launch_bounds__(256)
__global__ void k_channel(const float* __restrict__ att, const bf16* __restrict__ WctP,
                          const float* __restrict__ b_ch, const float* __restrict__ p_h,
                          const float* __restrict__ w_beta, float* __restrict__ logits_c) {
  __shared__ alignas(1024) char lds[CH_AOFF + 64 * CH_ASTR];
  const int tid = threadIdx.x;
  const int lane = tid & 63;
  const int wn = tid >> 6;
  const int l15 = lane & 15, l4 = lane >> 4;
  const int b = blockIdx.y;
  const int h0 = blockIdx.x * 64;
  const float* attb = att + (size_t)b * Ll * 1024;
  const int slotB = ((l4 ^ ((l15 >> 1) & 3)) << 4);
  const char* WctPc = (const char*)WctP;

  // issue B panel 0 first (overlaps the A-transpose stage)
#pragma unroll
  for (int j = 0; j < 8; ++j) {
    int c = (j << 2) + wn;
    async16(WctPc + c * 1024 + lane * 16, &lds[c * 1024]);
  }

  // A-stage once: transpose att[b][l][h0..h0+63] -> lds[h][l] bf16
  {
    const int lsub = tid >> 4;               // l-pair 0..15
    const int hq = (tid & 15) << 2;          // h 0,4,...,60
#pragma unroll
    for (int ch = 0; ch < 7; ++ch) {
      int lg = ch * 32 + 2 * lsub;
      float4 va = {0.f, 0.f, 0.f, 0.f}, vb = {0.f, 0.f, 0.f, 0.f};
      if (lg < Ll)
        va = *reinterpret_cast<const float4*>(&attb[(size_t)lg * 1024 + h0 + hq]);
      if (lg + 1 < Ll)
        vb = *reinterpret_cast<const float4*>(&attb[(size_t)(lg + 1) * 1024 + h0 + hq]);
      uint32 p0 = packbf2(va.x, vb.x), p1 = packbf2(va.y, vb.y);
      uint32 p2 = packbf2(va.z, vb.z), p3 = packbf2(va.w, vb.w);
      char* abase = &lds[CH_AOFF + hq * CH_ASTR + lg * 2];
      *reinterpret_cast<uint32*>(abase) = p0;
      *reinterpret_cast<uint32*>(abase + CH_ASTR) = p1;
      *reinterpret_cast<uint32*>(abase + 2 * CH_ASTR) = p2;
      *reinterpret_cast<uint32*>(abase + 3 * CH_ASTR) = p3;
    }
  }

  f32x4 acc[4][8];
#pragma unroll
  for (int m = 0; m < 4; ++m)
#pragma unroll
    for (int n = 0; n < 8; ++n) acc[m][n] = f32x4{0.f, 0.f, 0.f, 0.f};
  __syncthreads();                            // A-tile + B0 ready

  for (int t7 = 0; t7 < 7; ++t7) {
    bf16x8 af[4];
#pragma unroll
    for (int m = 0; m < 4; ++m)
      af[m] = *reinterpret_cast<const bf16x8*>(
          &lds[CH_AOFF + (m * 16 + l15) * CH_ASTR + t7 * 64 + (l4 << 4)]);
#pragma unroll
    for (int n = 0; n < 8; ++n) {
      bf16x8 bv = *reinterpret_cast<const bf16x8*>(
          &lds[(wn * 128 + n * 16 + l15) * 64 + slotB]);
#pragma unroll
      for (int m = 0; m < 4; ++m)
        acc[m][n] = __builtin_amdgcn_mfma_f32_16x16x32_bf16(af[m], bv, acc[m][n], 0, 0, 0);
    }
    if (t7 < 6) {
      __syncthreads();                        // everyone done reading B(t7)
      const char* bsrc = WctPc + (size_t)(t7 + 1) * 32768;
#pragma unroll
      for (int j = 0; j < 8; ++j) {
        int c = (j << 2) + wn;
        async16(bsrc + c * 1024 + lane * 16, &lds[c * 1024]);
      }
      __syncthreads();                        // B(t7+1) ready
    }
  }
  __syncthreads();                            // before reusing lds for reduce

  // epilogue
  float wb[8], bc[8], ph[8];
#pragma unroll
  for (int n = 0; n < 8; ++n) {
    int a = wn * 128 + n * 16 + l15;
    wb[n] = w_beta[a];
    bc[n] = b_ch[a];
    ph[n] = p_h[(size_t)b * 512 + a];
  }
  float* red = reinterpret_cast<float*>(lds);
#pragma unroll
  for (int m = 0; m < 4; ++m) {
#pragma unroll
    for (int j = 0; j < 4; ++j) {
      int rloc = m * 16 + l4 * 4 + j;
      float s = 0.f;
#pragma unroll
      for (int n = 0; n < 8; ++n)
        s += fast_tanh(acc[m][n][j] + bc[n] + ph[n]) * wb[n];
      s += __shfl_xor(s, 1);
      s += __shfl_xor(s, 2);
      s += __shfl_xor(s, 4);
      s += __shfl_xor(s, 8);
      if (l15 == 0) red[wn * 64 + rloc] = s;
    }
  }
  __syncthreads();
  if (tid < 64)
    logits_c[(size_t)b * 1024 + h0 + tid] =
        red[tid] + red[64 + tid] + red[128 + tid] + red[192 + tid];
}

// ------------------------------- softmaxes ---------------------------------
__global__ void k_softmax_s(const float* __restrict__ logits, float* __restrict__ wout) {
  int b = blockIdx.x, t = threadIdx.x;
  __shared__ float sm[8];
  float x = (t < Ll) ? logits[(size_t)b * Ll + t] : -1e30f;
  float m = x;
#pragma unroll
  for (int o = 32; o; o >>= 1) m = fmaxf(m, __shfl_xor(m, o));
  if ((t & 63) == 0) sm[t >> 6] = m;
  __syncthreads();
  m = fmaxf(fmaxf(sm[0], sm[1]), fmaxf(sm[2], sm[3]));
  float e = (t < Ll) ? __expf(x - m) : 0.f;
  float s = e;
#pragma unroll
  for (int o = 32; o; o >>= 1) s += __shfl_xor(s, o);
  if ((t & 63) == 0) sm[4 + (t >> 6)] = s;
  __syncthreads();
  s = sm[4] + sm[5] + sm[6] + sm[7];
  if (t < Ll) wout[(size_t)b * Ll + t] = e / s;
}

__global__ void k_softmax_c(const float* __restrict__ logits, float* __restrict__ wout) {
  int b = blockIdx.x, t = threadIdx.x;
  __shared__ float sm[8];
  float4 x = *reinterpret_cast<const float4*>(&logits[(size_t)b * 1024 + (t << 2)]);
  float m = fmaxf(fmaxf(x.x, x.y), fmaxf(x.z, x.w));
#pragma unroll
  for (int o = 32; o; o >>= 1) m = fmaxf(m, __shfl_xor(m, o));
  if ((t & 63) == 0) sm[t >> 6] = m;
  __syncthreads();
  m = fmaxf(fmaxf(sm[0], sm[1]), fmaxf(sm[2], sm[3]));
  float e0 = __expf(x.x - m), e1 = __expf(x.y - m);
  float e2 = __expf(x.z - m), e3 = __expf(x.w - m);
  float s = e0 + e1 + e2 + e3;
#pragma unroll
  for (int o = 32; o; o >>= 1) s += __shfl_xor(s, o);
  if ((t & 63) == 0) sm[4 + (t >> 6)] = s;
  __syncthreads();
  float r = 1.f / (sm[4] + sm[5] + sm[6] + sm[7]);
  float4 o4 = {e0 * r, e1 * r, e2 * r, e3 * r};
  *reinterpret_cast<float4*>(&wout[(size_t)b * 1024 + (t << 2)]) = o4;
}

// --------------- fused weighted sums: one pass over att --------------------
__launch_bounds__(256)
__global__ void k_weighted(const float* __restrict__ att, const float* __restrict__ wsp,
                           const float* __restrict__ wch, float* __restrict__ out_s,
                           float* __restrict__ out_c) {
  int b = blockIdx.x, t = threadIdx.x;
  int lane = t & 63, wave = t >> 6;
  __shared__ float wsl[Ll];
  __shared__ float chan[4][Ll];
  if (t < Ll) wsl[t] = wsp[(size_t)b * Ll + t];
  float4 wc = *reinterpret_cast<const float4*>(&wch[(size_t)b * 1024 + (t << 2)]);
  float4 accs = {0.f, 0.f, 0.f, 0.f};
  __syncthreads();
  const float* attb = att + (size_t)b * Ll * 1024;
  for (int l = 0; l < Ll; ++l) {
    float4 v = *reinterpret_cast<const float4*>(&attb[(size_t)l * 1024 + (t << 2)]);
    float w = wsl[l];
    accs.x += w * v.x; accs.y += w * v.y; accs.z += w * v.z; accs.w += w * v.w;
    float pc = wc.x * v.x + wc.y * v.y + wc.z * v.z + wc.w * v.w;
#pragma unroll
    for (int o = 32; o; o >>= 1) pc += __shfl_xor(pc, o);
    if (lane == 0) chan[wave][l] = pc;
  }
  *reinterpret_cast<float4*>(&out_s[(size_t)b * 1024 + (t << 2)]) = accs;
  __syncthreads();
  if (t < Ll)
    out_c[(size_t)b * Ll + t] = chan[0][t] + chan[1][t] + chan[2][t] + chan[3][t];
}

// ------------------------------- launcher ----------------------------------
extern "C" void kernel_launch(void* const* d_in, const int* in_sizes, int n_in,
                              void* d_out, int out_size, void* d_ws, size_t ws_size,
                              hipStream_t stream) {
  (void)in_sizes; (void)n_in; (void)out_size; (void)ws_size;
  const float* att     = (const float*)d_in[0];
  const float* h       = (const float*)d_in[1];
  const float* W_att   = (const float*)d_in[2];
  const float* b_att   = (const float*)d_in[3];
  const float* W_h     = (const float*)d_in[4];
  const float* b_h     = (const float*)d_in[5];
  const float* w_alpha = (const float*)d_in[6];
  const float* W_ch    = (const float*)d_in[8];
  const float* b_ch    = (const float*)d_in[9];
  const float* w_beta  = (const float*)d_in[10];
  // d_in[7] b_alpha, d_in[11] b_beta: softmax-shift-invariant, unused

  float* out_ws    = (float*)d_out;                       // [B,H]
  float* out_wc    = out_ws + (size_t)Bb * Hh;            // [B,L]
  float* out_wspat = out_wc + (size_t)Bb * Ll;            // [B,L]

  char* ws = (char*)d_ws;
  float* p_h      = (float*)(ws);                          // 2 MB
  float* logits_s = (float*)(ws + 2097152);                // 802816 B
  float* logits_c = (float*)(ws + 2899968);                // 4 MB
  float* w_chan   = (float*)(ws + 7094272);                // 4 MB
  bf16*  WtP      = (bf16*)(ws + 11288576);                // 1 MB (32 panels)
  bf16*  WctP     = (bf16*)(ws + 12337152);                // 224 KB (7 panels)

  k_build_wt<<<256, 256, 0, stream>>>(W_att, WtP);
  k_build_wct<<<56, 256, 0, stream>>>(W_ch, WctP);
  k_ph<<<dim3(2, 128), 256, 0, stream>>>(h, W_h, b_h, p_h);
  k_spatial<<<BL / 64, 256, 0, stream>>>(att, WtP, b_att, p_h, w_alpha, logits_s);
  k_channel<<<dim3(16, 1024), 256, 0, stream>>>(att, WctP, b_ch, p_h, w_beta, logits_c);
  k_softmax_s<<<1024, 256, 0, stream>>>(logits_s, out_wspat);
  k_softmax_c<<<1024, 256, 0, stream>>>(logits_c, w_chan);
  k_weighted<<<1024, 256, 0, stream>>>(att, out_wspat, w_chan, out_ws, out_wc);
}